// Round 26
// baseline (194.425 us; speedup 1.0000x reference)
//
#include <hip/hip_runtime.h>
#include <hip/hip_bf16.h>
#include <stdint.h>

#define B_   2
#define T_   2048
#define H_   2048
#define NH_  16
#define NKV_ 4
#define HD_  128
#define M_   (B_*T_)
#define NQKV 3072
#define SCALE_  0.08838834764831845f
#define SCALE2_ (0.08838834764831845f * 1.4426950408889634f)   // scale * log2(e)

typedef __hip_bfloat16 bf16;
typedef __attribute__((ext_vector_type(8))) short bh8;
typedef __attribute__((ext_vector_type(4))) float f32x4;
typedef __attribute__((ext_vector_type(16))) float f32x16;
typedef __attribute__((ext_vector_type(4))) unsigned short us4;

__device__ __forceinline__ void gload16(const bf16* g, bf16* l) {
  __builtin_amdgcn_global_load_lds(
      (const __attribute__((address_space(1))) void*)g,
      (__attribute__((address_space(3))) void*)l, 16, 0, 0);
}

__device__ __forceinline__ void cstore(bf16* p, float v)  { *p = __float2bfloat16(v); }
__device__ __forceinline__ void cstore(float* p, float v) { *p = v; }

__device__ __forceinline__ void cvt8(const float* src, bf16* dst, int i) {
  const float4 a = *(const float4*)(src + i);
  const float4 b = *(const float4*)(src + i + 4);
  bf16 o[8];
  o[0]=__float2bfloat16(a.x); o[1]=__float2bfloat16(a.y);
  o[2]=__float2bfloat16(a.z); o[3]=__float2bfloat16(a.w);
  o[4]=__float2bfloat16(b.x); o[5]=__float2bfloat16(b.y);
  o[6]=__float2bfloat16(b.z); o[7]=__float2bfloat16(b.w);
  *(bh8*)(dst + i) = *(const bh8*)o;
}

// ALL fp32->bf16 converts in one launch. Weight dsts are contiguous regions of
// one [3072][2048] concat (Wq rows 0-2047, Wk 2048-2559, Wv 2560-3071).
__global__ __launch_bounds__(256) void cvtall(
    const float* __restrict__ x, bf16* __restrict__ xo,
    const float* __restrict__ q, bf16* __restrict__ qo,
    const float* __restrict__ o, bf16* __restrict__ oo,
    const float* __restrict__ k, bf16* __restrict__ ko,
    const float* __restrict__ v, bf16* __restrict__ vo)
{
  const int b = blockIdx.x;
  const float* src; bf16* dst; int n, b0, gb;
  if (b < 2048)      { src=x; dst=xo; n=M_*H_;        b0=b;      gb=2048; }
  else if (b < 2560) { src=q; dst=qo; n=NH_*HD_*H_;   b0=b-2048; gb=512; }
  else if (b < 3072) { src=o; dst=oo; n=H_*NH_*HD_;   b0=b-2560; gb=512; }
  else if (b < 3200) { src=k; dst=ko; n=NKV_*HD_*H_;  b0=b-3072; gb=128; }
  else               { src=v; dst=vo; n=NKV_*HD_*H_;  b0=b-3200; gb=128; }
  const int stride = gb * 256 * 8;
  for (int i = (b0*256 + threadIdx.x)*8; i < n; i += stride)
    cvt8(src, dst, i);
}

// ---------------------------------------------------------------------------
// 256x192 4-phase GEMM (fused QKV) with 32x32x16 MFMA (2382 TF ceiling vs
// 2075 for 16x16). Waves 4m x 2n -> per-wave 64x96 = 2x3 tiles of 32x32.
// Staging schedule / vmcnt identical to the validated 4-phase 16x16 version;
// only fragment reads, accumulators, MFMA and epilogue change.
// A/B frag: lane row(col)=lane&31, k=(lane>>5)*8+j, slot = ks*2+(lane>>5),
// XOR (l31&7).  C/D: col=lane&31, row=(reg&3)+8*(reg>>2)+4*(lane>>5).
// ---------------------------------------------------------------------------
__global__ __launch_bounds__(512, 2) void gemm_qkv192(
    const bf16* __restrict__ A, const bf16* __restrict__ Wcat,
    bf16* __restrict__ C, int cpx)
{
  const int bid = (int)(blockIdx.x & 7) * cpx + (int)(blockIdx.x >> 3);  // T1
  const int m0 = (bid >> 4) * 256;
  const int n0 = (bid & 15) * 192;
  const bf16* Ag = A    + (size_t)m0 * H_;
  const bf16* W  = Wcat + (size_t)n0 * H_;

  const int tid = threadIdx.x, lane = tid & 63, w = tid >> 6;
  const int wm = w >> 1;        // 0..3 (4 m-waves, 64 rows each)
  const int wn = w & 1;         // 0..1 (2 n-waves, 96 cols each)
  const int l31 = lane & 31;
  const int hi  = lane >> 5;    // 0..1
  const int sx  = l31 & 7;      // swizzle key (rows are 8-aligned)

  __shared__ bf16 LA[2][256*64];   // 2 x 32 KiB
  __shared__ bf16 LB[2][192*64];   // 2 x 24 KiB

  f32x16 acc[2][3] = {};
  bh8 bfr[3][4];                   // [n-tile][kstep]

  #define STGA(DST, KT, HALF)                                                       \
    { _Pragma("unroll")                                                             \
      for (int i_ = 0; i_ < 2; ++i_) {                                              \
        const int o_ = i_*512 + tid; const int r_ = o_ >> 3; const int sl_ = o_ & 7;\
        gload16(Ag + (size_t)((HALF)*128 + r_)*H_ + (KT)*64 + ((sl_ ^ (r_ & 7)) << 3), \
                (DST) + (HALF)*8192 + o_*8);                                        \
      } }
  #define STGB2(DST, KT)                                                            \
    { _Pragma("unroll")                                                             \
      for (int i_ = 0; i_ < 2; ++i_) {                                              \
        const int o_ = i_*512 + tid; const int r_ = o_ >> 3; const int sl_ = o_ & 7;\
        gload16(W + (size_t)r_*H_ + (KT)*64 + ((sl_ ^ (r_ & 7)) << 3),              \
                (DST) + o_*8);                                                      \
      } }
  #define STGB1(DST, KT)                                                            \
    {   const int o_ = 1024 + tid; const int r_ = o_ >> 3; const int sl_ = o_ & 7;  \
        gload16(W + (size_t)r_*H_ + (KT)*64 + ((sl_ ^ (r_ & 7)) << 3),              \
                (DST) + o_*8);                                                      \
    }

  // prologue: LA0<-kt0 (4), LB0<-kt0 (3), LB1<-kt1 (3); vmcnt(3) keeps LB1.
  STGA(LA[0], 0, 0); STGA(LA[0], 0, 1);
  STGB2(LB[0], 0);   STGB1(LB[0], 0);
  STGB2(LB[1], 1);   STGB1(LB[1], 1);
  asm volatile("s_waitcnt vmcnt(3)" ::: "memory");
  __builtin_amdgcn_s_barrier();

  // One phase = one m-tile (32 rows) x 3 n-tiles x 4 ksteps = 12 MFMA.
  #define PHASE4(MT, RBUF, DOB, STAGE_STMT, CHK)                                    \
    {                                                                               \
      if (DOB) {                                                                    \
        _Pragma("unroll") for (int nt=0;nt<3;++nt)                                  \
        _Pragma("unroll") for (int ks=0;ks<4;++ks) {                                \
          const int rB = wn*96 + nt*32 + l31;                                       \
          bfr[nt][ks] = *(const bh8*)&LB[RBUF][rB*64 + (((ks*2 + hi) ^ sx) << 3)];  \
        }                                                                           \
      }                                                                             \
      bh8 af_[4];                                                                   \
      _Pragma("unroll") for (int ks=0;ks<4;++ks) {                                  \
        const int rA = wm*64 + (MT)*32 + l31;                                       \
        af_[ks] = *(const bh8*)&LA[RBUF][rA*64 + (((ks*2 + hi) ^ sx) << 3)];        \
      }                                                                             \
      STAGE_STMT;                                                                   \
      __builtin_amdgcn_s_barrier();                                                 \
      asm volatile("s_waitcnt lgkmcnt(0)" ::: "memory");                            \
      __builtin_amdgcn_sched_barrier(0);                                            \
      __builtin_amdgcn_s_setprio(1);                                                \
      _Pragma("unroll") for (int nt=0;nt<3;++nt)                                    \
      _Pragma("unroll") for (int ks=0;ks<4;++ks)                                    \
        acc[MT][nt] = __builtin_amdgcn_mfma_f32_32x32x16_bf16(af_[ks], bfr[nt][ks], acc[MT][nt], 0,0,0); \
      __builtin_amdgcn_s_setprio(0);                                                \
      if (CHK) { asm volatile("s_waitcnt vmcnt(3)" ::: "memory"); }                 \
      __builtin_amdgcn_s_barrier();                                                 \
    }

  for (int j = 0; j < 16; ++j) {
    const int kta = (2*j + 1);
    const int ktb = (2*j + 2) & 31;
    const int ktc = (2*j + 3) & 31;
    PHASE4(0, 0, true , { STGA(LA[1], kta, 0) STGA(LA[1], kta, 1) }, false)
    PHASE4(1, 0, false, { STGB2(LB[0], ktb)   STGB1(LB[0], ktb)   }, true )
    PHASE4(0, 1, true , { STGA(LA[0], ktb, 0) STGA(LA[0], ktb, 1) }, false)
    PHASE4(1, 1, false, { STGB2(LB[1], ktc)   STGB1(LB[1], ktc)   }, true )
  }
  #undef PHASE4
  #undef STGA
  #undef STGB2
  #undef STGB1

  // epilogue: C/D mapping col=lane&31, row=(reg&3)+8*(reg>>2)+4*hi
  #pragma unroll
  for (int mt = 0; mt < 2; ++mt)
    #pragma unroll
    for (int nt = 0; nt < 3; ++nt)
      #pragma unroll
      for (int rg = 0; rg < 16; ++rg) {
        const int row = m0 + wm*64 + mt*32 + (rg & 3) + 8*(rg >> 2) + 4*hi;
        const int col = n0 + wn*96 + nt*32 + l31;
        cstore(&C[(size_t)row*NQKV + col], acc[mt][nt][rg]);
      }
}

// ---------------------------------------------------------------------------
// 256x128 4-phase GEMM (O-proj), 16x16 MFMA, unchanged from round 25.
// ---------------------------------------------------------------------------
template<typename OutT>
__global__ __launch_bounds__(512, 2) void gemm_n128(
    const bf16* __restrict__ A, const bf16* __restrict__ Wm, OutT* __restrict__ C,
    int K, int nbN, int N, int cpx)
{
  const int bid = (int)(blockIdx.x & 7) * cpx + (int)(blockIdx.x >> 3);
  const int m0 = (bid / nbN) * 256;
  const int n0 = (bid % nbN) * 128;
  const bf16* W  = Wm + (size_t)n0 * K;
  const bf16* Ag = A  + (size_t)m0 * K;

  const int tid = threadIdx.x, lane = tid & 63, w = tid >> 6;
  const int wm = w >> 2, wn = w & 3;
  const int l15 = lane & 15, g = lane >> 4;
  const int swz = l15 & 7;

  __shared__ bf16 LA[2][256*64];
  __shared__ bf16 LB[2][128*64];

  f32x4 acc[8][2] = {};
  bh8 bfr[2][2];

  const int ktmask = (K >> 6) - 1;
  const int niter  = K >> 7;

  #define STG2(DST, SRC, KT, HALF)                                                  \
    { _Pragma("unroll")                                                             \
      for (int i_ = 0; i_ < 2; ++i_) {                                              \
        const int o_ = i_*512 + tid; const int r_ = o_ >> 3; const int sl_ = o_ & 7;\
        gload16((SRC) + (size_t)((HALF)*128 + r_)*K + (KT)*64 + ((sl_ ^ (r_ & 7)) << 3), \
                (DST) + (HALF)*8192 + o_*8);                                        \
      } }

  STG2(LA[0], Ag, 0, 0); STG2(LA[0], Ag, 0, 1);
  STG2(LB[0], W,  0, 0);
  STG2(LB[1], W,  1, 0);
  asm volatile("s_waitcnt vmcnt(2)" ::: "memory");
  __builtin_amdgcn_s_barrier();

  #define PH4(MI0, RBUF, DOB, STAGE_STMT, CHK)                                      \
    {                                                                               \
      if (DOB) {                                                                    \
        _Pragma("unroll") for (int nj=0;nj<2;++nj)                                  \
        _Pragma("unroll") for (int ks=0;ks<2;++ks)                                  \
          bfr[nj][ks] = *(const bh8*)&LB[RBUF][(wn*32+nj*16+l15)*64 + (((ks*4+g)^swz)<<3)]; \
      }                                                                             \
      bh8 af_[4][2];                                                                \
      _Pragma("unroll") for (int mi=0;mi<4;++mi)                                    \
      _Pragma("unroll") for (int ks=0;ks<2;++ks)                                    \
        af_[mi][ks] = *(const bh8*)&LA[RBUF][(wm*128+((MI0)+mi)*16+l15)*64 + (((ks*4+g)^swz)<<3)]; \
      STAGE_STMT;                                                                   \
      __builtin_amdgcn_s_barrier();                                                 \
      asm volatile("s_waitcnt lgkmcnt(0)" ::: "memory");                            \
      __builtin_amdgcn_sched_barrier(0);                                            \
      __builtin_amdgcn_s_setprio(1);                                                \
      _Pragma("unroll") for (int mi=0;mi<4;++mi)                                    \
      _Pragma("unroll") for (int nj=0;nj<2;++nj) {                                  \
        acc[(MI0)+mi][nj] = __builtin_amdgcn_mfma_f32_16x16x32_bf16(af_[mi][0], bfr[nj][0], acc[(MI0)+mi][nj],0,0,0); \
        acc[(MI0)+mi][nj] = __builtin_amdgcn_mfma_f32_16x16x32_bf16(af_[mi][1], bfr[nj][1], acc[(MI0)+mi][nj],0,0,0); \
      }                                                                             \
      __builtin_amdgcn_s_setprio(0);                                                \
      if (CHK) { asm volatile("s_waitcnt vmcnt(2)" ::: "memory"); }                 \
      __builtin_amdgcn_s_barrier();                                                 \
    }

  for (int j = 0; j < niter; ++j) {
    const int kta = 2*j + 1;
    const int ktb = (2*j + 2) & ktmask;
    const int ktc = (2*j + 3) & ktmask;
    PH4(0, 0, true , { STG2(LA[1], Ag, kta, 0) STG2(LA[1], Ag, kta, 1) }, false)
    PH4(4, 0, false, { STG2(LB[0], W,  ktb, 0) },                         true )
    PH4(0, 1, true , { STG2(LA[0], Ag, ktb, 0) STG2(LA[0], Ag, ktb, 1) }, false)
    PH4(4, 1, false, { STG2(LB[1], W,  ktc, 0) },                         true )
  }
  #undef PH4
  #undef STG2

  #pragma unroll
  for (int mi = 0; mi < 8; ++mi)
    #pragma unroll
    for (int r = 0; r < 4; ++r) {
      const int row = m0 + wm*128 + mi*16 + (lane>>4)*4 + r;
      #pragma unroll
      for (int nj = 0; nj < 2; ++nj) {
        const int col = n0 + wn*32 + nj*16 + l15;
        cstore(&C[(size_t)row*N + col], acc[mi][nj][r]);
      }
    }
}

// Per (b,t): RMSNorm(HD) + RoPE IN PLACE on qkv[4096][3072].
__global__ __launch_bounds__(256) void postproc(
    bf16* __restrict__ qkv,
    const float* __restrict__ qw, const float* __restrict__ kw)
{
  const int blk  = blockIdx.x;
  const int t    = blk & (T_-1);
  const int lane = threadIdx.x & 63;
  const int w    = threadIdx.x >> 6;

  const float inv = expf(-(float)lane * (9.210340371976184f / 64.f));
  const float ang = (float)t * inv;
  const float cw = cosf(ang), sw = sinf(ang);

  #pragma unroll
  for (int hi = 0; hi < 4; ++hi) {
    const int h = w + hi*4;
    bf16* row = qkv + (size_t)blk*NQKV + h*HD_;
    float x1 = __bfloat162float(row[lane]);
    float x2 = __bfloat162float(row[lane+64]);
    float ss = x1*x1 + x2*x2;
    #pragma unroll
    for (int m = 1; m < 64; m <<= 1) ss += __shfl_xor(ss, m, 64);
    const float rs = rsqrtf(ss*(1.f/128.f) + 1e-6f);
    const float n1 = x1*rs*(1.f + qw[lane]), n2 = x2*rs*(1.f + qw[lane+64]);
    row[lane]    = __float2bfloat16((n1*cw - n2*sw) * SCALE2_);
    row[lane+64] = __float2bfloat16((n2*cw + n1*sw) * SCALE2_);
  }
  {
    bf16* row = qkv + (size_t)blk*NQKV + 2048 + w*HD_;
    float x1 = __bfloat162float(row[lane]);
    float x2 = __bfloat162float(row[lane+64]);
    float ss = x1*x1 + x2*x2;
    #pragma unroll
    for (int m = 1; m < 64; m <<= 1) ss += __shfl_xor(ss, m, 64);
    const float rs = rsqrtf(ss*(1.f/128.f) + 1e-6f);
    const float n1 = x1*rs*(1.f + kw[lane]), n2 = x2*rs*(1.f + kw[lane+64]);
    row[lane]    = __float2bfloat16(n1*cw - n2*sw);
    row[lane+64] = __float2bfloat16(n2*cw + n1*sw);
  }
}

// V (qkv cols 2560..3071) -> Vt [b][kvh][d][T]
__global__ __launch_bounds__(256) void vtrans(const bf16* __restrict__ qkv,
                                              bf16* __restrict__ Vt)
{
  __shared__ bf16 tile[64][65];
  const int t0 = blockIdx.x * 64;
  const int c0 = blockIdx.y * 64;
  const int b  = blockIdx.z;
  const int tx = threadIdx.x & 63;
  const int ty = threadIdx.x >> 6;
  const bf16* src = qkv + (size_t)b * T_ * NQKV + 2560;
  bf16* dst       = Vt  + (size_t)b * (NKV_*HD_) * T_;
  #pragma unroll
  for (int i = 0; i < 16; ++i) {
    const int r = i*4 + ty;
    tile[r][tx] = src[(size_t)(t0 + r)*NQKV + c0 + tx];
  }
  __syncthreads();
  #pragma unroll
  for (int i = 0; i < 16; ++i) {
    const int r = i*4 + ty;
    dst[(size_t)(c0 + r)*T_ + t0 + tx] = tile[tx][r];
  }
}

// Flash attention v10 (best measured): unchanged.
__global__ __launch_bounds__(512, 4) void attn(
    const bf16* __restrict__ qkv, const bf16* __restrict__ Vt,
    bf16* __restrict__ att)
{
  const int id   = blockIdx.x;         // 0..511
  const int hlf  = id >> 8;
  const int q_   = id & 255;
  const int s    = hlf ? (q_ >> 2) : (63 - (q_ >> 2));
  const int sub  = (id & 3) | (hlf << 2);
  const int kvh  = sub >> 1;
  const int b    = sub & 1;
  const int tid = threadIdx.x, lane = tid & 63, w = tid >> 6;
  const int h   = kvh*4 + (w & 3);
  const int l15 = lane & 15;
  const int g   = lane >> 4;
  const int lr4 = g * 4;
  const int swz = l15 & 7;

  const int q0w = s*32 + (w >> 2)*16;
  const int nt  = (s >> 1) + 1;

  __shared__ bf16 Ks[2][64*128];
  __shared__ bf16 Vs[2][128*64];
  __shared__ bf16 Plds[8][16*64];

  const bf16* Kglob = qkv + (size_t)b*T_*NQKV + 2048 + kvh*HD_;
  const bf16* Vglob = Vt  + (size_t)(b*NKV_ + kvh)*HD_*T_;

  bh8 aQ[4];
  #pragma unroll
  for (int kk = 0; kk < 4; ++kk)
    aQ[kk] = *(const bh8*)&qkv[(size_t)(b*T_ + q0w + l15)*NQKV + h*HD_ + kk*32 + g*8];

  f32x4 acc[8] = {};
  float lL = 0.f;

  #define STAGE_KV(buf, kv0s)                                                   \
    {                                                                           \
      _Pragma("unroll")                                                         \
      for (int i = 0; i < 2; ++i) {                                             \
        const int o = i*512 + tid;                                              \
        const int r = o >> 4, sl = o & 15;                                      \
        gload16(Kglob + (size_t)((kv0s) + r)*NQKV + ((sl ^ (r & 7)) << 3),      \
                &Ks[buf][o*8]);                                                 \
      }                                                                         \
      _Pragma("unroll")                                                         \
      for (int i = 0; i < 2; ++i) {                                             \
        const int o = i*512 + tid;                                              \
        const int d = o >> 3, sl = o & 7;                                       \
        gload16(Vglob + (size_t)d*T_ + (kv0s) + ((sl ^ (d & 7)) << 3),          \
                &Vs[buf][o*8]);                                                 \
      }                                                                         \
    }

  STAGE_KV(0, 0);
  asm volatile("s_waitcnt vmcnt(0)" ::: "memory");
  __syncthreads();

  for (int j = 0; j < nt; ++j) {
    const int cur = j & 1;
    const int kv0 = j*64;

    if (j + 1 < nt) STAGE_KV(cur ^ 1, kv0 + 64);

    f32x4 S[4] = {};
    #pragma unroll
    for (int jb = 0; jb < 4; ++jb)
      #pragma unroll
      for (int kk = 0; kk < 4; ++kk) {
        const bh8 kf = *(const bh8*)&Ks[cur][(jb*16 + l15)*128 + (((kk*4 + g) ^ swz) << 3)];
        S[jb] = __builtin_amdgcn_mfma_f32_16x16x32_bf16(kf, aQ[kk], S[jb], 0,0,0);
      }

    const bool diag = (j == nt - 1);
    float sv[16];
    float sum = 0.f;
    #pragma unroll
    for (int jb = 0; jb < 4; ++jb)
      #pragma unroll
      for (int r = 0; r < 4; ++r) {
        float sc = S[jb][r];
        if (diag && (kv0 + jb*16 + lr4 + r) > (q0w + l15)) sc = -1e30f;
        const float p = exp2f(sc);
        sv[jb*4 + r] = p;
        sum += p;
      }
    lL += sum;

    bf16* pl = Plds[w];
    #pragma unroll
    for (int jb = 0; jb < 4; ++jb) {
      bf16 pk[4];
      #pragma unroll
      for (int r = 0; r < 4; ++r) pk[r] = __float2bfloat16(sv[jb*4 + r]);
      *(us4*)((char*)pl + l15*128 + ((((jb<<1) | (g>>1)) ^ swz) << 4) + ((g&1) << 3))
          = *(const us4*)pk;
    }

    asm volatile("s_waitcnt lgkmcnt(0)" ::: "memory");
    __builtin_amdgcn_sched_barrier(0);

    const bh8 pa0 = *(const bh8*)((const char*)pl + l15*128 + (((g    ) ^ swz) << 4));
    const bh8 pa1 = *(const bh8*)((const char*)pl + l15*128 + (((4 + g) ^ swz) << 4));
    #pragma unroll
    for (int jd = 0; jd < 8; ++jd) {
      const bh8 vf0 = *(const bh8*)&Vs[cur][(jd*16 + l15)*64 + (((g    ) ^ swz) << 3)];
      const bh8 vf1 = *(const bh8*)&Vs[cur][(jd*16 + l15)*64 + (((4 + g) ^ swz) << 3)];
      acc[jd] = __builtin_amdgcn_mfma_f32_16x16x32_bf16(pa0, vf0, acc[jd], 0,0,0);
      acc[jd] = __builtin_amdgcn_mfma_f32_16x16x32_bf16(pa1, vf1, acc[jd], 0,0,0);
    }

    asm volatile("s_waitcnt vmcnt(0)" ::: "memory");
    __syncthreads();
  }
  #undef STAGE_KV

  lL += __shfl_xor(lL, 16, 64);
  lL += __shfl_xor(lL, 32, 64);
  float lar[4];
  #pragma unroll
  for (int r = 0; r < 4; ++r)
    lar[r] = __shfl(lL, (lane & 48) | (lr4 + r), 64);
  #pragma unroll
  for (int r = 0; r < 4; ++r) {
    const float inv = 1.f / lar[r];
    const int row = q0w + lr4 + r;
    bf16* orow = att + ((size_t)(b*T_ + row))*(NH_*HD_) + h*HD_;
    #pragma unroll
    for (int jd = 0; jd < 8; ++jd)
      orow[jd*16 + l15] = __float2bfloat16(acc[jd][r] * inv);
  }
}

extern "C" void kernel_launch(void* const* d_in, const int* in_sizes, int n_in,
                              void* d_out, int out_size, void* d_ws, size_t ws_size,
                              hipStream_t stream) {
  const float* x  = (const float*)d_in[0];
  const float* Wq = (const float*)d_in[1];
  const float* Wk = (const float*)d_in[2];
  const float* Wv = (const float*)d_in[3];
  const float* Wo = (const float*)d_in[4];
  const float* qw = (const float*)d_in[5];
  const float* kw = (const float*)d_in[6];
  float* out = (float*)d_out;

  char* ws = (char*)d_ws;
  bf16* xb   = (bf16*)(ws);                  // 16MB, becomes att later
  // Wqb/Wkb/Wvb form one contiguous [3072][2048] weight concat:
  bf16* Wqb  = (bf16*)(ws + (16u<<20));      // 8MB (rows 0-2047)
  bf16* Wkb  = (bf16*)(ws + (24u<<20));      // 2MB (rows 2048-2559)
  bf16* Wvb  = (bf16*)(ws + (26u<<20));      // 2MB (rows 2560-3071)
  bf16* Wob  = (bf16*)(ws + (28u<<20));      // 8MB
  bf16* Vt   = (bf16*)(ws + (44u<<20));      // 4MB
  bf16* att  = xb;
  bf16* qkv  = (bf16*)d_out;                 // [4096][3072] bf16 = 24MB in d_out

  cvtall<<<dim3(3328), 256, 0, stream>>>(x, xb, Wq, Wqb, Wo, Wob, Wk, Wkb, Wv, Wvb);

  // fused QKV: 256 blocks (16m x 16n of 256x192), 1 block/CU, cpx = 32
  gemm_qkv192<<<dim3(256), 512, 0, stream>>>(xb, Wqb, qkv, 32);
  postproc<<<dim3(M_), 256, 0, stream>>>(qkv, qw, kw);
  vtrans<<<dim3(T_/64, (NKV_*HD_)/64, B_), 256, 0, stream>>>(qkv, Vt);
  attn<<<dim3(512), 512, 0, stream>>>(qkv, Vt, att);
  // O-proj: 256 blocks (16m x 16n), XCD-chunked (cpx = 32), fp32 out
  gemm_n128<float><<<dim3(256), 512, 0, stream>>>(att, Wob, out, 2048, 16, 2048, 32);
}

// Round 27
// 189.891 us; speedup vs baseline: 1.0239x; 1.0239x over previous
//
#include <hip/hip_runtime.h>
#include <hip/hip_bf16.h>
#include <stdint.h>

#define B_   2
#define T_   2048
#define H_   2048
#define NH_  16
#define NKV_ 4
#define HD_  128
#define M_   (B_*T_)
#define NQKV 3072
#define SCALE_  0.08838834764831845f
#define SCALE2_ (0.08838834764831845f * 1.4426950408889634f)   // scale * log2(e)

typedef __hip_bfloat16 bf16;
typedef __attribute__((ext_vector_type(8))) short bh8;
typedef __attribute__((ext_vector_type(4))) float f32x4;
typedef __attribute__((ext_vector_type(4))) unsigned short us4;

__device__ __forceinline__ void gload16(const bf16* g, bf16* l) {
  __builtin_amdgcn_global_load_lds(
      (const __attribute__((address_space(1))) void*)g,
      (__attribute__((address_space(3))) void*)l, 16, 0, 0);
}

__device__ __forceinline__ void cstore(bf16* p, float v)  { *p = __float2bfloat16(v); }
__device__ __forceinline__ void cstore(float* p, float v) { *p = v; }

__device__ __forceinline__ void cvt8(const float* src, bf16* dst, int i) {
  const float4 a = *(const float4*)(src + i);
  const float4 b = *(const float4*)(src + i + 4);
  bf16 o[8];
  o[0]=__float2bfloat16(a.x); o[1]=__float2bfloat16(a.y);
  o[2]=__float2bfloat16(a.z); o[3]=__float2bfloat16(a.w);
  o[4]=__float2bfloat16(b.x); o[5]=__float2bfloat16(b.y);
  o[6]=__float2bfloat16(b.z); o[7]=__float2bfloat16(b.w);
  *(bh8*)(dst + i) = *(const bh8*)o;
}

// ALL fp32->bf16 converts in one launch. Weight dsts are contiguous regions of
// one [3072][2048] concat (Wq rows 0-2047, Wk 2048-2559, Wv 2560-3071).
__global__ __launch_bounds__(256) void cvtall(
    const float* __restrict__ x, bf16* __restrict__ xo,
    const float* __restrict__ q, bf16* __restrict__ qo,
    const float* __restrict__ o, bf16* __restrict__ oo,
    const float* __restrict__ k, bf16* __restrict__ ko,
    const float* __restrict__ v, bf16* __restrict__ vo)
{
  const int b = blockIdx.x;
  const float* src; bf16* dst; int n, b0, gb;
  if (b < 2048)      { src=x; dst=xo; n=M_*H_;        b0=b;      gb=2048; }
  else if (b < 2560) { src=q; dst=qo; n=NH_*HD_*H_;   b0=b-2048; gb=512; }
  else if (b < 3072) { src=o; dst=oo; n=H_*NH_*HD_;   b0=b-2560; gb=512; }
  else if (b < 3200) { src=k; dst=ko; n=NKV_*HD_*H_;  b0=b-3072; gb=128; }
  else               { src=v; dst=vo; n=NKV_*HD_*H_;  b0=b-3200; gb=128; }
  const int stride = gb * 256 * 8;
  for (int i = (b0*256 + threadIdx.x)*8; i < n; i += stride)
    cvt8(src, dst, i);
}

// ---------------------------------------------------------------------------
// 256x192 4-phase GEMM (fused QKV): C[4096][3072] = A[4096][2048] x W^T.
// 24 MFMA/phase (16x16x32), stages {ph1: LA1<-kta, ph2: LB0<-ktb,
// ph3: LA0<-ktb, ph4: LB1<-ktc}, vmcnt(3) at ph2/ph4 (queue never empties).
// Round-26 lesson: 32x32 MFMA port regressed (acc-chain ILP too low at
// 2 waves/SIMD) -- keep 16x16 with 8 independent accumulators per phase.
// ---------------------------------------------------------------------------
__global__ __launch_bounds__(512, 2) void gemm_qkv192(
    const bf16* __restrict__ A, const bf16* __restrict__ Wcat,
    bf16* __restrict__ C, int cpx)
{
  const int bid = (int)(blockIdx.x & 7) * cpx + (int)(blockIdx.x >> 3);  // T1
  const int m0 = (bid >> 4) * 256;
  const int n0 = (bid & 15) * 192;
  const bf16* Ag = A    + (size_t)m0 * H_;
  const bf16* W  = Wcat + (size_t)n0 * H_;

  const int tid = threadIdx.x, lane = tid & 63, w = tid >> 6;
  const int wm = w >> 2, wn = w & 3;
  const int l15 = lane & 15, g = lane >> 4;
  const int swz = l15 & 7;

  __shared__ bf16 LA[2][256*64];   // 2 x 32 KiB
  __shared__ bf16 LB[2][192*64];   // 2 x 24 KiB

  f32x4 acc[8][3] = {};
  bh8 bfr[3][2];

  #define STGA(DST, KT, HALF)                                                       \
    { _Pragma("unroll")                                                             \
      for (int i_ = 0; i_ < 2; ++i_) {                                              \
        const int o_ = i_*512 + tid; const int r_ = o_ >> 3; const int sl_ = o_ & 7;\
        gload16(Ag + (size_t)((HALF)*128 + r_)*H_ + (KT)*64 + ((sl_ ^ (r_ & 7)) << 3), \
                (DST) + (HALF)*8192 + o_*8);                                        \
      } }
  #define STGB2(DST, KT)                                                            \
    { _Pragma("unroll")                                                             \
      for (int i_ = 0; i_ < 2; ++i_) {                                              \
        const int o_ = i_*512 + tid; const int r_ = o_ >> 3; const int sl_ = o_ & 7;\
        gload16(W + (size_t)r_*H_ + (KT)*64 + ((sl_ ^ (r_ & 7)) << 3),              \
                (DST) + o_*8);                                                      \
      } }
  #define STGB1(DST, KT)                                                            \
    {   const int o_ = 1024 + tid; const int r_ = o_ >> 3; const int sl_ = o_ & 7;  \
        gload16(W + (size_t)r_*H_ + (KT)*64 + ((sl_ ^ (r_ & 7)) << 3),              \
                (DST) + o_*8);                                                      \
    }

  // prologue: LA0<-kt0 (4), LB0<-kt0 (3), LB1<-kt1 (3); vmcnt(3) keeps LB1.
  STGA(LA[0], 0, 0); STGA(LA[0], 0, 1);
  STGB2(LB[0], 0);   STGB1(LB[0], 0);
  STGB2(LB[1], 1);   STGB1(LB[1], 1);
  asm volatile("s_waitcnt vmcnt(3)" ::: "memory");
  __builtin_amdgcn_s_barrier();

  #define PHASE4(MI0, RBUF, DOB, STAGE_STMT, CHK)                                   \
    {                                                                               \
      if (DOB) {                                                                    \
        _Pragma("unroll") for (int nj=0;nj<3;++nj)                                  \
        _Pragma("unroll") for (int ks=0;ks<2;++ks)                                  \
          bfr[nj][ks] = *(const bh8*)&LB[RBUF][(wn*48+nj*16+l15)*64 + (((ks*4+g)^swz)<<3)]; \
      }                                                                             \
      bh8 af_[4][2];                                                                \
      _Pragma("unroll") for (int mi=0;mi<4;++mi)                                    \
      _Pragma("unroll") for (int ks=0;ks<2;++ks)                                    \
        af_[mi][ks] = *(const bh8*)&LA[RBUF][(wm*128+((MI0)+mi)*16+l15)*64 + (((ks*4+g)^swz)<<3)]; \
      STAGE_STMT;                                                                   \
      __builtin_amdgcn_s_barrier();                                                 \
      asm volatile("s_waitcnt lgkmcnt(0)" ::: "memory");                            \
      __builtin_amdgcn_sched_barrier(0);                                            \
      __builtin_amdgcn_s_setprio(1);                                                \
      _Pragma("unroll") for (int mi=0;mi<4;++mi)                                    \
      _Pragma("unroll") for (int nj=0;nj<3;++nj) {                                  \
        acc[(MI0)+mi][nj] = __builtin_amdgcn_mfma_f32_16x16x32_bf16(af_[mi][0], bfr[nj][0], acc[(MI0)+mi][nj],0,0,0); \
        acc[(MI0)+mi][nj] = __builtin_amdgcn_mfma_f32_16x16x32_bf16(af_[mi][1], bfr[nj][1], acc[(MI0)+mi][nj],0,0,0); \
      }                                                                             \
      __builtin_amdgcn_s_setprio(0);                                                \
      if (CHK) { asm volatile("s_waitcnt vmcnt(3)" ::: "memory"); }                 \
      __builtin_amdgcn_s_barrier();                                                 \
    }

  for (int j = 0; j < 16; ++j) {
    const int kta = (2*j + 1);
    const int ktb = (2*j + 2) & 31;
    const int ktc = (2*j + 3) & 31;
    PHASE4(0, 0, true , { STGA(LA[1], kta, 0) STGA(LA[1], kta, 1) }, false)
    PHASE4(4, 0, false, { STGB2(LB[0], ktb)   STGB1(LB[0], ktb)   }, true )
    PHASE4(0, 1, true , { STGA(LA[0], ktb, 0) STGA(LA[0], ktb, 1) }, false)
    PHASE4(4, 1, false, { STGB2(LB[1], ktc)   STGB1(LB[1], ktc)   }, true )
  }
  #undef PHASE4
  #undef STGA
  #undef STGB2
  #undef STGB1

  #pragma unroll
  for (int mi = 0; mi < 8; ++mi)
    #pragma unroll
    for (int r = 0; r < 4; ++r) {
      const int row = m0 + wm*128 + mi*16 + (lane>>4)*4 + r;
      #pragma unroll
      for (int nj = 0; nj < 3; ++nj) {
        const int col = n0 + wn*48 + nj*16 + l15;
        cstore(&C[(size_t)row*NQKV + col], acc[mi][nj][r]);
      }
    }
}

// ---------------------------------------------------------------------------
// 256x128 4-phase GEMM (O-proj): 16 MFMA/phase, vmcnt(2) at ph2/ph4.
// ---------------------------------------------------------------------------
template<typename OutT>
__global__ __launch_bounds__(512, 2) void gemm_n128(
    const bf16* __restrict__ A, const bf16* __restrict__ Wm, OutT* __restrict__ C,
    int K, int nbN, int N, int cpx)
{
  const int bid = (int)(blockIdx.x & 7) * cpx + (int)(blockIdx.x >> 3);
  const int m0 = (bid / nbN) * 256;
  const int n0 = (bid % nbN) * 128;
  const bf16* W  = Wm + (size_t)n0 * K;
  const bf16* Ag = A  + (size_t)m0 * K;

  const int tid = threadIdx.x, lane = tid & 63, w = tid >> 6;
  const int wm = w >> 2, wn = w & 3;
  const int l15 = lane & 15, g = lane >> 4;
  const int swz = l15 & 7;

  __shared__ bf16 LA[2][256*64];
  __shared__ bf16 LB[2][128*64];

  f32x4 acc[8][2] = {};
  bh8 bfr[2][2];

  const int ktmask = (K >> 6) - 1;
  const int niter  = K >> 7;

  #define STG2(DST, SRC, KT, HALF)                                                  \
    { _Pragma("unroll")                                                             \
      for (int i_ = 0; i_ < 2; ++i_) {                                              \
        const int o_ = i_*512 + tid; const int r_ = o_ >> 3; const int sl_ = o_ & 7;\
        gload16((SRC) + (size_t)((HALF)*128 + r_)*K + (KT)*64 + ((sl_ ^ (r_ & 7)) << 3), \
                (DST) + (HALF)*8192 + o_*8);                                        \
      } }

  STG2(LA[0], Ag, 0, 0); STG2(LA[0], Ag, 0, 1);
  STG2(LB[0], W,  0, 0);
  STG2(LB[1], W,  1, 0);
  asm volatile("s_waitcnt vmcnt(2)" ::: "memory");
  __builtin_amdgcn_s_barrier();

  #define PH4(MI0, RBUF, DOB, STAGE_STMT, CHK)                                      \
    {                                                                               \
      if (DOB) {                                                                    \
        _Pragma("unroll") for (int nj=0;nj<2;++nj)                                  \
        _Pragma("unroll") for (int ks=0;ks<2;++ks)                                  \
          bfr[nj][ks] = *(const bh8*)&LB[RBUF][(wn*32+nj*16+l15)*64 + (((ks*4+g)^swz)<<3)]; \
      }                                                                             \
      bh8 af_[4][2];                                                                \
      _Pragma("unroll") for (int mi=0;mi<4;++mi)                                    \
      _Pragma("unroll") for (int ks=0;ks<2;++ks)                                    \
        af_[mi][ks] = *(const bh8*)&LA[RBUF][(wm*128+((MI0)+mi)*16+l15)*64 + (((ks*4+g)^swz)<<3)]; \
      STAGE_STMT;                                                                   \
      __builtin_amdgcn_s_barrier();                                                 \
      asm volatile("s_waitcnt lgkmcnt(0)" ::: "memory");                            \
      __builtin_amdgcn_sched_barrier(0);                                            \
      __builtin_amdgcn_s_setprio(1);                                                \
      _Pragma("unroll") for (int mi=0;mi<4;++mi)                                    \
      _Pragma("unroll") for (int nj=0;nj<2;++nj) {                                  \
        acc[(MI0)+mi][nj] = __builtin_amdgcn_mfma_f32_16x16x32_bf16(af_[mi][0], bfr[nj][0], acc[(MI0)+mi][nj],0,0,0); \
        acc[(MI0)+mi][nj] = __builtin_amdgcn_mfma_f32_16x16x32_bf16(af_[mi][1], bfr[nj][1], acc[(MI0)+mi][nj],0,0,0); \
      }                                                                             \
      __builtin_amdgcn_s_setprio(0);                                                \
      if (CHK) { asm volatile("s_waitcnt vmcnt(2)" ::: "memory"); }                 \
      __builtin_amdgcn_s_barrier();                                                 \
    }

  for (int j = 0; j < niter; ++j) {
    const int kta = 2*j + 1;
    const int ktb = (2*j + 2) & ktmask;
    const int ktc = (2*j + 3) & ktmask;
    PH4(0, 0, true , { STG2(LA[1], Ag, kta, 0) STG2(LA[1], Ag, kta, 1) }, false)
    PH4(4, 0, false, { STG2(LB[0], W,  ktb, 0) },                         true )
    PH4(0, 1, true , { STG2(LA[0], Ag, ktb, 0) STG2(LA[0], Ag, ktb, 1) }, false)
    PH4(4, 1, false, { STG2(LB[1], W,  ktc, 0) },                         true )
  }
  #undef PH4
  #undef STG2

  #pragma unroll
  for (int mi = 0; mi < 8; ++mi)
    #pragma unroll
    for (int r = 0; r < 4; ++r) {
      const int row = m0 + wm*128 + mi*16 + (lane>>4)*4 + r;
      #pragma unroll
      for (int nj = 0; nj < 2; ++nj) {
        const int col = n0 + wn*32 + nj*16 + l15;
        cstore(&C[(size_t)row*N + col], acc[mi][nj][r]);
      }
    }
}

// Per (b,t): RMSNorm(HD) + RoPE IN PLACE on qkv[4096][3072].
__global__ __launch_bounds__(256) void postproc(
    bf16* __restrict__ qkv,
    const float* __restrict__ qw, const float* __restrict__ kw)
{
  const int blk  = blockIdx.x;
  const int t    = blk & (T_-1);
  const int lane = threadIdx.x & 63;
  const int w    = threadIdx.x >> 6;

  const float inv = expf(-(float)lane * (9.210340371976184f / 64.f));
  const float ang = (float)t * inv;
  const float cw = cosf(ang), sw = sinf(ang);

  #pragma unroll
  for (int hi = 0; hi < 4; ++hi) {
    const int h = w + hi*4;
    bf16* row = qkv + (size_t)blk*NQKV + h*HD_;
    float x1 = __bfloat162float(row[lane]);
    float x2 = __bfloat162float(row[lane+64]);
    float ss = x1*x1 + x2*x2;
    #pragma unroll
    for (int m = 1; m < 64; m <<= 1) ss += __shfl_xor(ss, m, 64);
    const float rs = rsqrtf(ss*(1.f/128.f) + 1e-6f);
    const float n1 = x1*rs*(1.f + qw[lane]), n2 = x2*rs*(1.f + qw[lane+64]);
    row[lane]    = __float2bfloat16((n1*cw - n2*sw) * SCALE2_);
    row[lane+64] = __float2bfloat16((n2*cw + n1*sw) * SCALE2_);
  }
  {
    bf16* row = qkv + (size_t)blk*NQKV + 2048 + w*HD_;
    float x1 = __bfloat162float(row[lane]);
    float x2 = __bfloat162float(row[lane+64]);
    float ss = x1*x1 + x2*x2;
    #pragma unroll
    for (int m = 1; m < 64; m <<= 1) ss += __shfl_xor(ss, m, 64);
    const float rs = rsqrtf(ss*(1.f/128.f) + 1e-6f);
    const float n1 = x1*rs*(1.f + kw[lane]), n2 = x2*rs*(1.f + kw[lane+64]);
    row[lane]    = __float2bfloat16(n1*cw - n2*sw);
    row[lane+64] = __float2bfloat16(n2*cw + n1*sw);
  }
}

// V (qkv cols 2560..3071) -> Vt [b][kvh][d][T]
__global__ __launch_bounds__(256) void vtrans(const bf16* __restrict__ qkv,
                                              bf16* __restrict__ Vt)
{
  __shared__ bf16 tile[64][65];
  const int t0 = blockIdx.x * 64;
  const int c0 = blockIdx.y * 64;
  const int b  = blockIdx.z;
  const int tx = threadIdx.x & 63;
  const int ty = threadIdx.x >> 6;
  const bf16* src = qkv + (size_t)b * T_ * NQKV + 2560;
  bf16* dst       = Vt  + (size_t)b * (NKV_*HD_) * T_;
  #pragma unroll
  for (int i = 0; i < 16; ++i) {
    const int r = i*4 + ty;
    tile[r][tx] = src[(size_t)(t0 + r)*NQKV + c0 + tx];
  }
  __syncthreads();
  #pragma unroll
  for (int i = 0; i < 16; ++i) {
    const int r = i*4 + ty;
    dst[(size_t)(c0 + r)*T_ + t0 + tx] = tile[tx][r];
  }
}

// Flash attention v10 (best measured): unchanged.
__global__ __launch_bounds__(512, 4) void attn(
    const bf16* __restrict__ qkv, const bf16* __restrict__ Vt,
    bf16* __restrict__ att)
{
  const int id   = blockIdx.x;         // 0..511
  const int hlf  = id >> 8;
  const int q_   = id & 255;
  const int s    = hlf ? (q_ >> 2) : (63 - (q_ >> 2));
  const int sub  = (id & 3) | (hlf << 2);
  const int kvh  = sub >> 1;
  const int b    = sub & 1;
  const int tid = threadIdx.x, lane = tid & 63, w = tid >> 6;
  const int h   = kvh*4 + (w & 3);
  const int l15 = lane & 15;
  const int g   = lane >> 4;
  const int lr4 = g * 4;
  const int swz = l15 & 7;

  const int q0w = s*32 + (w >> 2)*16;
  const int nt  = (s >> 1) + 1;

  __shared__ bf16 Ks[2][64*128];
  __shared__ bf16 Vs[2][128*64];
  __shared__ bf16 Plds[8][16*64];

  const bf16* Kglob = qkv + (size_t)b*T_*NQKV + 2048 + kvh*HD_;
  const bf16* Vglob = Vt  + (size_t)(b*NKV_ + kvh)*HD_*T_;

  bh8 aQ[4];
  #pragma unroll
  for (int kk = 0; kk < 4; ++kk)
    aQ[kk] = *(const bh8*)&qkv[(size_t)(b*T_ + q0w + l15)*NQKV + h*HD_ + kk*32 + g*8];

  f32x4 acc[8] = {};
  float lL = 0.f;

  #define STAGE_KV(buf, kv0s)                                                   \
    {                                                                           \
      _Pragma("unroll")                                                         \
      for (int i = 0; i < 2; ++i) {                                             \
        const int o = i*512 + tid;                                              \
        const int r = o >> 4, sl = o & 15;                                      \
        gload16(Kglob + (size_t)((kv0s) + r)*NQKV + ((sl ^ (r & 7)) << 3),      \
                &Ks[buf][o*8]);                                                 \
      }                                                                         \
      _Pragma("unroll")                                                         \
      for (int i = 0; i < 2; ++i) {                                             \
        const int o = i*512 + tid;                                              \
        const int d = o >> 3, sl = o & 7;                                       \
        gload16(Vglob + (size_t)d*T_ + (kv0s) + ((sl ^ (d & 7)) << 3),          \
                &Vs[buf][o*8]);                                                 \
      }                                                                         \
    }

  STAGE_KV(0, 0);
  asm volatile("s_waitcnt vmcnt(0)" ::: "memory");
  __syncthreads();

  for (int j = 0; j < nt; ++j) {
    const int cur = j & 1;
    const int kv0 = j*64;

    if (j + 1 < nt) STAGE_KV(cur ^ 1, kv0 + 64);

    f32x4 S[4] = {};
    #pragma unroll
    for (int jb = 0; jb < 4; ++jb)
      #pragma unroll
      for (int kk = 0; kk < 4; ++kk) {
        const bh8 kf = *(const bh8*)&Ks[cur][(jb*16 + l15)*128 + (((kk*4 + g) ^ swz) << 3)];
        S[jb] = __builtin_amdgcn_mfma_f32_16x16x32_bf16(kf, aQ[kk], S[jb], 0,0,0);
      }

    const bool diag = (j == nt - 1);
    float sv[16];
    float sum = 0.f;
    #pragma unroll
    for (int jb = 0; jb < 4; ++jb)
      #pragma unroll
      for (int r = 0; r < 4; ++r) {
        float sc = S[jb][r];
        if (diag && (kv0 + jb*16 + lr4 + r) > (q0w + l15)) sc = -1e30f;
        const float p = exp2f(sc);
        sv[jb*4 + r] = p;
        sum += p;
      }
    lL += sum;

    bf16* pl = Plds[w];
    #pragma unroll
    for (int jb = 0; jb < 4; ++jb) {
      bf16 pk[4];
      #pragma unroll
      for (int r = 0; r < 4; ++r) pk[r] = __float2bfloat16(sv[jb*4 + r]);
      *(us4*)((char*)pl + l15*128 + ((((jb<<1) | (g>>1)) ^ swz) << 4) + ((g&1) << 3))
          = *(const us4*)pk;
    }

    asm volatile("s_waitcnt lgkmcnt(0)" ::: "memory");
    __builtin_amdgcn_sched_barrier(0);

    const bh8 pa0 = *(const bh8*)((const char*)pl + l15*128 + (((g    ) ^ swz) << 4));
    const bh8 pa1 = *(const bh8*)((const char*)pl + l15*128 + (((4 + g) ^ swz) << 4));
    #pragma unroll
    for (int jd = 0; jd < 8; ++jd) {
      const bh8 vf0 = *(const bh8*)&Vs[cur][(jd*16 + l15)*64 + (((g    ) ^ swz) << 3)];
      const bh8 vf1 = *(const bh8*)&Vs[cur][(jd*16 + l15)*64 + (((4 + g) ^ swz) << 3)];
      acc[jd] = __builtin_amdgcn_mfma_f32_16x16x32_bf16(pa0, vf0, acc[jd], 0,0,0);
      acc[jd] = __builtin_amdgcn_mfma_f32_16x16x32_bf16(pa1, vf1, acc[jd], 0,0,0);
    }

    asm volatile("s_waitcnt vmcnt(0)" ::: "memory");
    __syncthreads();
  }
  #undef STAGE_KV

  lL += __shfl_xor(lL, 16, 64);
  lL += __shfl_xor(lL, 32, 64);
  float lar[4];
  #pragma unroll
  for (int r = 0; r < 4; ++r)
    lar[r] = __shfl(lL, (lane & 48) | (lr4 + r), 64);
  #pragma unroll
  for (int r = 0; r < 4; ++r) {
    const float inv = 1.f / lar[r];
    const int row = q0w + lr4 + r;
    bf16* orow = att + ((size_t)(b*T_ + row))*(NH_*HD_) + h*HD_;
    #pragma unroll
    for (int jd = 0; jd < 8; ++jd)
      orow[jd*16 + l15] = __float2bfloat16(acc[jd][r] * inv);
  }
}

extern "C" void kernel_launch(void* const* d_in, const int* in_sizes, int n_in,
                              void* d_out, int out_size, void* d_ws, size_t ws_size,
                              hipStream_t stream) {
  const float* x  = (const float*)d_in[0];
  const float* Wq = (const float*)d_in[1];
  const float* Wk = (const float*)d_in[2];
  const float* Wv = (const float*)d_in[3];
  const float* Wo = (const float*)d_in[4];
  const float* qw = (const float*)d_in[5];
  const float* kw = (const float*)d_in[6];
  float* out = (float*)d_out;

  char* ws = (char*)d_ws;
  bf16* xb   = (bf16*)(ws);                  // 16MB, becomes att later
  // Wqb/Wkb/Wvb form one contiguous [3072][2048] weight concat:
  bf16* Wqb  = (bf16*)(ws + (16u<<20));      // 8MB (rows 0-2047)
  bf16* Wkb  = (bf16*)(ws + (24u<<20));      // 2MB (rows 2048-2559)
  bf16* Wvb  = (bf16*)(ws + (26u<<20));      // 2MB (rows 2560-3071)
  bf16* Wob  = (bf16*)(ws + (28u<<20));      // 8MB
  bf16* Vt   = (bf16*)(ws + (44u<<20));      // 4MB
  bf16* att  = xb;
  bf16* qkv  = (bf16*)d_out;                 // [4096][3072] bf16 = 24MB in d_out

  cvtall<<<dim3(3328), 256, 0, stream>>>(x, xb, Wq, Wqb, Wo, Wob, Wk, Wkb, Wv, Wvb);

  // fused QKV: 256 blocks (16m x 16n of 256x192), 1 block/CU, cpx = 32
  gemm_qkv192<<<dim3(256), 512, 0, stream>>>(xb, Wqb, qkv, 32);
  postproc<<<dim3(M_), 256, 0, stream>>>(qkv, qw, kw);
  vtrans<<<dim3(T_/64, (NKV_*HD_)/64, B_), 256, 0, stream>>>(qkv, Vt);
  attn<<<dim3(512), 512, 0, stream>>>(qkv, Vt, att);
  // O-proj: 256 blocks (16m x 16n), XCD-chunked (cpx = 32), fp32 out
  gemm_n128<float><<<dim3(256), 512, 0, stream>>>(att, Wob, out, 2048, 16, 2048, 32);
}

// Round 28
// 186.657 us; speedup vs baseline: 1.0416x; 1.0173x over previous
//
#include <hip/hip_runtime.h>
#include <hip/hip_bf16.h>
#include <stdint.h>

#define B_   2
#define T_   2048
#define H_   2048
#define NH_  16
#define NKV_ 4
#define HD_  128
#define M_   (B_*T_)
#define NQKV 3072
#define SCALE_  0.08838834764831845f
#define SCALE2_ (0.08838834764831845f * 1.4426950408889634f)   // scale * log2(e)

typedef __hip_bfloat16 bf16;
typedef __attribute__((ext_vector_type(8))) short bh8;
typedef __attribute__((ext_vector_type(4))) float f32x4;
typedef __attribute__((ext_vector_type(4))) unsigned short us4;

__device__ __forceinline__ void gload16(const bf16* g, bf16* l) {
  __builtin_amdgcn_global_load_lds(
      (const __attribute__((address_space(1))) void*)g,
      (__attribute__((address_space(3))) void*)l, 16, 0, 0);
}

__device__ __forceinline__ void cstore(bf16* p, float v)  { *p = __float2bfloat16(v); }
__device__ __forceinline__ void cstore(float* p, float v) { *p = v; }

__device__ __forceinline__ void cvt8(const float* src, bf16* dst, int i) {
  const float4 a = *(const float4*)(src + i);
  const float4 b = *(const float4*)(src + i + 4);
  bf16 o[8];
  o[0]=__float2bfloat16(a.x); o[1]=__float2bfloat16(a.y);
  o[2]=__float2bfloat16(a.z); o[3]=__float2bfloat16(a.w);
  o[4]=__float2bfloat16(b.x); o[5]=__float2bfloat16(b.y);
  o[6]=__float2bfloat16(b.z); o[7]=__float2bfloat16(b.w);
  *(bh8*)(dst + i) = *(const bh8*)o;
}

// ALL fp32->bf16 converts in one launch. Weight dsts are contiguous regions of
// one [3072][2048] concat (Wq rows 0-2047, Wk 2048-2559, Wv 2560-3071).
__global__ __launch_bounds__(256) void cvtall(
    const float* __restrict__ x, bf16* __restrict__ xo,
    const float* __restrict__ q, bf16* __restrict__ qo,
    const float* __restrict__ o, bf16* __restrict__ oo,
    const float* __restrict__ k, bf16* __restrict__ ko,
    const float* __restrict__ v, bf16* __restrict__ vo)
{
  const int b = blockIdx.x;
  const float* src; bf16* dst; int n, b0, gb;
  if (b < 2048)      { src=x; dst=xo; n=M_*H_;        b0=b;      gb=2048; }
  else if (b < 2560) { src=q; dst=qo; n=NH_*HD_*H_;   b0=b-2048; gb=512; }
  else if (b < 3072) { src=o; dst=oo; n=H_*NH_*HD_;   b0=b-2560; gb=512; }
  else if (b < 3200) { src=k; dst=ko; n=NKV_*HD_*H_;  b0=b-3072; gb=128; }
  else               { src=v; dst=vo; n=NKV_*HD_*H_;  b0=b-3200; gb=128; }
  const int stride = gb * 256 * 8;
  for (int i = (b0*256 + threadIdx.x)*8; i < n; i += stride)
    cvt8(src, dst, i);
}

// ---------------------------------------------------------------------------
// 256x192 4-phase GEMM (fused QKV): C[4096][3072] = A[4096][2048] x W^T.
// 24 MFMA/phase (16x16x32), stages {ph1: LA1<-kta, ph2: LB0<-ktb,
// ph3: LA0<-ktb, ph4: LB1<-ktc}, vmcnt(3) at ph2/ph4 (queue never empties).
// Round-26 lesson: 32x32 MFMA port regressed (acc-chain ILP too low at
// 2 waves/SIMD) -- keep 16x16 with 8 independent accumulators per phase.
// ---------------------------------------------------------------------------
__global__ __launch_bounds__(512, 2) void gemm_qkv192(
    const bf16* __restrict__ A, const bf16* __restrict__ Wcat,
    bf16* __restrict__ C, int cpx)
{
  const int bid = (int)(blockIdx.x & 7) * cpx + (int)(blockIdx.x >> 3);  // T1
  const int m0 = (bid >> 4) * 256;
  const int n0 = (bid & 15) * 192;
  const bf16* Ag = A    + (size_t)m0 * H_;
  const bf16* W  = Wcat + (size_t)n0 * H_;

  const int tid = threadIdx.x, lane = tid & 63, w = tid >> 6;
  const int wm = w >> 2, wn = w & 3;
  const int l15 = lane & 15, g = lane >> 4;
  const int swz = l15 & 7;

  __shared__ bf16 LA[2][256*64];   // 2 x 32 KiB
  __shared__ bf16 LB[2][192*64];   // 2 x 24 KiB

  f32x4 acc[8][3] = {};
  bh8 bfr[3][2];

  #define STGA(DST, KT, HALF)                                                       \
    { _Pragma("unroll")                                                             \
      for (int i_ = 0; i_ < 2; ++i_) {                                              \
        const int o_ = i_*512 + tid; const int r_ = o_ >> 3; const int sl_ = o_ & 7;\
        gload16(Ag + (size_t)((HALF)*128 + r_)*H_ + (KT)*64 + ((sl_ ^ (r_ & 7)) << 3), \
                (DST) + (HALF)*8192 + o_*8);                                        \
      } }
  #define STGB2(DST, KT)                                                            \
    { _Pragma("unroll")                                                             \
      for (int i_ = 0; i_ < 2; ++i_) {                                              \
        const int o_ = i_*512 + tid; const int r_ = o_ >> 3; const int sl_ = o_ & 7;\
        gload16(W + (size_t)r_*H_ + (KT)*64 + ((sl_ ^ (r_ & 7)) << 3),              \
                (DST) + o_*8);                                                      \
      } }
  #define STGB1(DST, KT)                                                            \
    {   const int o_ = 1024 + tid; const int r_ = o_ >> 3; const int sl_ = o_ & 7;  \
        gload16(W + (size_t)r_*H_ + (KT)*64 + ((sl_ ^ (r_ & 7)) << 3),              \
                (DST) + o_*8);                                                      \
    }

  // prologue: LA0<-kt0 (4), LB0<-kt0 (3), LB1<-kt1 (3); vmcnt(3) keeps LB1.
  STGA(LA[0], 0, 0); STGA(LA[0], 0, 1);
  STGB2(LB[0], 0);   STGB1(LB[0], 0);
  STGB2(LB[1], 1);   STGB1(LB[1], 1);
  asm volatile("s_waitcnt vmcnt(3)" ::: "memory");
  __builtin_amdgcn_s_barrier();

  #define PHASE4(MI0, RBUF, DOB, STAGE_STMT, CHK)                                   \
    {                                                                               \
      if (DOB) {                                                                    \
        _Pragma("unroll") for (int nj=0;nj<3;++nj)                                  \
        _Pragma("unroll") for (int ks=0;ks<2;++ks)                                  \
          bfr[nj][ks] = *(const bh8*)&LB[RBUF][(wn*48+nj*16+l15)*64 + (((ks*4+g)^swz)<<3)]; \
      }                                                                             \
      bh8 af_[4][2];                                                                \
      _Pragma("unroll") for (int mi=0;mi<4;++mi)                                    \
      _Pragma("unroll") for (int ks=0;ks<2;++ks)                                    \
        af_[mi][ks] = *(const bh8*)&LA[RBUF][(wm*128+((MI0)+mi)*16+l15)*64 + (((ks*4+g)^swz)<<3)]; \
      STAGE_STMT;                                                                   \
      __builtin_amdgcn_s_barrier();                                                 \
      asm volatile("s_waitcnt lgkmcnt(0)" ::: "memory");                            \
      __builtin_amdgcn_sched_barrier(0);                                            \
      __builtin_amdgcn_s_setprio(1);                                                \
      _Pragma("unroll") for (int mi=0;mi<4;++mi)                                    \
      _Pragma("unroll") for (int nj=0;nj<3;++nj) {                                  \
        acc[(MI0)+mi][nj] = __builtin_amdgcn_mfma_f32_16x16x32_bf16(af_[mi][0], bfr[nj][0], acc[(MI0)+mi][nj],0,0,0); \
        acc[(MI0)+mi][nj] = __builtin_amdgcn_mfma_f32_16x16x32_bf16(af_[mi][1], bfr[nj][1], acc[(MI0)+mi][nj],0,0,0); \
      }                                                                             \
      __builtin_amdgcn_s_setprio(0);                                                \
      if (CHK) { asm volatile("s_waitcnt vmcnt(3)" ::: "memory"); }                 \
      __builtin_amdgcn_s_barrier();                                                 \
    }

  for (int j = 0; j < 16; ++j) {
    const int kta = (2*j + 1);
    const int ktb = (2*j + 2) & 31;
    const int ktc = (2*j + 3) & 31;
    PHASE4(0, 0, true , { STGA(LA[1], kta, 0) STGA(LA[1], kta, 1) }, false)
    PHASE4(4, 0, false, { STGB2(LB[0], ktb)   STGB1(LB[0], ktb)   }, true )
    PHASE4(0, 1, true , { STGA(LA[0], ktb, 0) STGA(LA[0], ktb, 1) }, false)
    PHASE4(4, 1, false, { STGB2(LB[1], ktc)   STGB1(LB[1], ktc)   }, true )
  }
  #undef PHASE4
  #undef STGA
  #undef STGB2
  #undef STGB1

  #pragma unroll
  for (int mi = 0; mi < 8; ++mi)
    #pragma unroll
    for (int r = 0; r < 4; ++r) {
      const int row = m0 + wm*128 + mi*16 + (lane>>4)*4 + r;
      #pragma unroll
      for (int nj = 0; nj < 3; ++nj) {
        const int col = n0 + wn*48 + nj*16 + l15;
        cstore(&C[(size_t)row*NQKV + col], acc[mi][nj][r]);
      }
    }
}

// ---------------------------------------------------------------------------
// 256x128 4-phase GEMM (O-proj): 16 MFMA/phase, vmcnt(2) at ph2/ph4.
// ---------------------------------------------------------------------------
template<typename OutT>
__global__ __launch_bounds__(512, 2) void gemm_n128(
    const bf16* __restrict__ A, const bf16* __restrict__ Wm, OutT* __restrict__ C,
    int K, int nbN, int N, int cpx)
{
  const int bid = (int)(blockIdx.x & 7) * cpx + (int)(blockIdx.x >> 3);
  const int m0 = (bid / nbN) * 256;
  const int n0 = (bid % nbN) * 128;
  const bf16* W  = Wm + (size_t)n0 * K;
  const bf16* Ag = A  + (size_t)m0 * K;

  const int tid = threadIdx.x, lane = tid & 63, w = tid >> 6;
  const int wm = w >> 2, wn = w & 3;
  const int l15 = lane & 15, g = lane >> 4;
  const int swz = l15 & 7;

  __shared__ bf16 LA[2][256*64];
  __shared__ bf16 LB[2][128*64];

  f32x4 acc[8][2] = {};
  bh8 bfr[2][2];

  const int ktmask = (K >> 6) - 1;
  const int niter  = K >> 7;

  #define STG2(DST, SRC, KT, HALF)                                                  \
    { _Pragma("unroll")                                                             \
      for (int i_ = 0; i_ < 2; ++i_) {                                              \
        const int o_ = i_*512 + tid; const int r_ = o_ >> 3; const int sl_ = o_ & 7;\
        gload16((SRC) + (size_t)((HALF)*128 + r_)*K + (KT)*64 + ((sl_ ^ (r_ & 7)) << 3), \
                (DST) + (HALF)*8192 + o_*8);                                        \
      } }

  STG2(LA[0], Ag, 0, 0); STG2(LA[0], Ag, 0, 1);
  STG2(LB[0], W,  0, 0);
  STG2(LB[1], W,  1, 0);
  asm volatile("s_waitcnt vmcnt(2)" ::: "memory");
  __builtin_amdgcn_s_barrier();

  #define PH4(MI0, RBUF, DOB, STAGE_STMT, CHK)                                      \
    {                                                                               \
      if (DOB) {                                                                    \
        _Pragma("unroll") for (int nj=0;nj<2;++nj)                                  \
        _Pragma("unroll") for (int ks=0;ks<2;++ks)                                  \
          bfr[nj][ks] = *(const bh8*)&LB[RBUF][(wn*32+nj*16+l15)*64 + (((ks*4+g)^swz)<<3)]; \
      }                                                                             \
      bh8 af_[4][2];                                                                \
      _Pragma("unroll") for (int mi=0;mi<4;++mi)                                    \
      _Pragma("unroll") for (int ks=0;ks<2;++ks)                                    \
        af_[mi][ks] = *(const bh8*)&LA[RBUF][(wm*128+((MI0)+mi)*16+l15)*64 + (((ks*4+g)^swz)<<3)]; \
      STAGE_STMT;                                                                   \
      __builtin_amdgcn_s_barrier();                                                 \
      asm volatile("s_waitcnt lgkmcnt(0)" ::: "memory");                            \
      __builtin_amdgcn_sched_barrier(0);                                            \
      __builtin_amdgcn_s_setprio(1);                                                \
      _Pragma("unroll") for (int mi=0;mi<4;++mi)                                    \
      _Pragma("unroll") for (int nj=0;nj<2;++nj) {                                  \
        acc[(MI0)+mi][nj] = __builtin_amdgcn_mfma_f32_16x16x32_bf16(af_[mi][0], bfr[nj][0], acc[(MI0)+mi][nj],0,0,0); \
        acc[(MI0)+mi][nj] = __builtin_amdgcn_mfma_f32_16x16x32_bf16(af_[mi][1], bfr[nj][1], acc[(MI0)+mi][nj],0,0,0); \
      }                                                                             \
      __builtin_amdgcn_s_setprio(0);                                                \
      if (CHK) { asm volatile("s_waitcnt vmcnt(2)" ::: "memory"); }                 \
      __builtin_amdgcn_s_barrier();                                                 \
    }

  for (int j = 0; j < niter; ++j) {
    const int kta = 2*j + 1;
    const int ktb = (2*j + 2) & ktmask;
    const int ktc = (2*j + 3) & ktmask;
    PH4(0, 0, true , { STG2(LA[1], Ag, kta, 0) STG2(LA[1], Ag, kta, 1) }, false)
    PH4(4, 0, false, { STG2(LB[0], W,  ktb, 0) },                         true )
    PH4(0, 1, true , { STG2(LA[0], Ag, ktb, 0) STG2(LA[0], Ag, ktb, 1) }, false)
    PH4(4, 1, false, { STG2(LB[1], W,  ktc, 0) },                         true )
  }
  #undef PH4
  #undef STG2

  #pragma unroll
  for (int mi = 0; mi < 8; ++mi)
    #pragma unroll
    for (int r = 0; r < 4; ++r) {
      const int row = m0 + wm*128 + mi*16 + (lane>>4)*4 + r;
      #pragma unroll
      for (int nj = 0; nj < 2; ++nj) {
        const int col = n0 + wn*32 + nj*16 + l15;
        cstore(&C[(size_t)row*N + col], acc[mi][nj][r]);
      }
    }
}

// Merged postproc + vtrans (correctness-validated in round 23):
// blocks [0,4096): per-(b,t) RMSNorm+RoPE in place on qkv;
// blocks [4096,4608): V transpose (qkv cols 2560.. -> Vt).
__global__ __launch_bounds__(256) void postvt(
    bf16* __restrict__ qkv, bf16* __restrict__ Vt,
    const float* __restrict__ qw, const float* __restrict__ kw)
{
  __shared__ bf16 tile[64][65];
  const int blk = blockIdx.x;
  if (blk < 4096) {
    const int t    = blk & (T_-1);
    const int lane = threadIdx.x & 63;
    const int w    = threadIdx.x >> 6;

    const float inv = expf(-(float)lane * (9.210340371976184f / 64.f));
    const float ang = (float)t * inv;
    const float cw = cosf(ang), sw = sinf(ang);

    #pragma unroll
    for (int hi = 0; hi < 4; ++hi) {
      const int h = w + hi*4;
      bf16* row = qkv + (size_t)blk*NQKV + h*HD_;
      float x1 = __bfloat162float(row[lane]);
      float x2 = __bfloat162float(row[lane+64]);
      float ss = x1*x1 + x2*x2;
      #pragma unroll
      for (int m = 1; m < 64; m <<= 1) ss += __shfl_xor(ss, m, 64);
      const float rs = rsqrtf(ss*(1.f/128.f) + 1e-6f);
      const float n1 = x1*rs*(1.f + qw[lane]), n2 = x2*rs*(1.f + qw[lane+64]);
      row[lane]    = __float2bfloat16((n1*cw - n2*sw) * SCALE2_);
      row[lane+64] = __float2bfloat16((n2*cw + n1*sw) * SCALE2_);
    }
    {
      bf16* row = qkv + (size_t)blk*NQKV + 2048 + w*HD_;
      float x1 = __bfloat162float(row[lane]);
      float x2 = __bfloat162float(row[lane+64]);
      float ss = x1*x1 + x2*x2;
      #pragma unroll
      for (int m = 1; m < 64; m <<= 1) ss += __shfl_xor(ss, m, 64);
      const float rs = rsqrtf(ss*(1.f/128.f) + 1e-6f);
      const float n1 = x1*rs*(1.f + kw[lane]), n2 = x2*rs*(1.f + kw[lane+64]);
      row[lane]    = __float2bfloat16(n1*cw - n2*sw);
      row[lane+64] = __float2bfloat16(n2*cw + n1*sw);
    }
  } else {
    const int id2 = blk - 4096;                 // 0..511
    const int t0 = (id2 & 31) * 64;
    const int c0 = ((id2 >> 5) & 7) * 64;
    const int b  = id2 >> 8;
    const int tx = threadIdx.x & 63;
    const int ty = threadIdx.x >> 6;
    const bf16* src = qkv + (size_t)b * T_ * NQKV + 2560;
    bf16* dst       = Vt  + (size_t)b * (NKV_*HD_) * T_;
    #pragma unroll
    for (int i = 0; i < 16; ++i) {
      const int r = i*4 + ty;
      tile[r][tx] = src[(size_t)(t0 + r)*NQKV + c0 + tx];
    }
    __syncthreads();
    #pragma unroll
    for (int i = 0; i < 16; ++i) {
      const int r = i*4 + ty;
      dst[(size_t)(c0 + r)*T_ + t0 + tx] = tile[tx][r];
    }
  }
}

// Flash attention v10 (best measured): unchanged.
__global__ __launch_bounds__(512, 4) void attn(
    const bf16* __restrict__ qkv, const bf16* __restrict__ Vt,
    bf16* __restrict__ att)
{
  const int id   = blockIdx.x;         // 0..511
  const int hlf  = id >> 8;
  const int q_   = id & 255;
  const int s    = hlf ? (q_ >> 2) : (63 - (q_ >> 2));
  const int sub  = (id & 3) | (hlf << 2);
  const int kvh  = sub >> 1;
  const int b    = sub & 1;
  const int tid = threadIdx.x, lane = tid & 63, w = tid >> 6;
  const int h   = kvh*4 + (w & 3);
  const int l15 = lane & 15;
  const int g   = lane >> 4;
  const int lr4 = g * 4;
  const int swz = l15 & 7;

  const int q0w = s*32 + (w >> 2)*16;
  const int nt  = (s >> 1) + 1;

  __shared__ bf16 Ks[2][64*128];
  __shared__ bf16 Vs[2][128*64];
  __shared__ bf16 Plds[8][16*64];

  const bf16* Kglob = qkv + (size_t)b*T_*NQKV + 2048 + kvh*HD_;
  const bf16* Vglob = Vt  + (size_t)(b*NKV_ + kvh)*HD_*T_;

  bh8 aQ[4];
  #pragma unroll
  for (int kk = 0; kk < 4; ++kk)
    aQ[kk] = *(const bh8*)&qkv[(size_t)(b*T_ + q0w + l15)*NQKV + h*HD_ + kk*32 + g*8];

  f32x4 acc[8] = {};
  float lL = 0.f;

  #define STAGE_KV(buf, kv0s)                                                   \
    {                                                                           \
      _Pragma("unroll")                                                         \
      for (int i = 0; i < 2; ++i) {                                             \
        const int o = i*512 + tid;                                              \
        const int r = o >> 4, sl = o & 15;                                      \
        gload16(Kglob + (size_t)((kv0s) + r)*NQKV + ((sl ^ (r & 7)) << 3),      \
                &Ks[buf][o*8]);                                                 \
      }                                                                         \
      _Pragma("unroll")                                                         \
      for (int i = 0; i < 2; ++i) {                                             \
        const int o = i*512 + tid;                                              \
        const int d = o >> 3, sl = o & 7;                                       \
        gload16(Vglob + (size_t)d*T_ + (kv0s) + ((sl ^ (d & 7)) << 3),          \
                &Vs[buf][o*8]);                                                 \
      }                                                                         \
    }

  STAGE_KV(0, 0);
  asm volatile("s_waitcnt vmcnt(0)" ::: "memory");
  __syncthreads();

  for (int j = 0; j < nt; ++j) {
    const int cur = j & 1;
    const int kv0 = j*64;

    if (j + 1 < nt) STAGE_KV(cur ^ 1, kv0 + 64);

    f32x4 S[4] = {};
    #pragma unroll
    for (int jb = 0; jb < 4; ++jb)
      #pragma unroll
      for (int kk = 0; kk < 4; ++kk) {
        const bh8 kf = *(const bh8*)&Ks[cur][(jb*16 + l15)*128 + (((kk*4 + g) ^ swz) << 3)];
        S[jb] = __builtin_amdgcn_mfma_f32_16x16x32_bf16(kf, aQ[kk], S[jb], 0,0,0);
      }

    const bool diag = (j == nt - 1);
    float sv[16];
    float sum = 0.f;
    #pragma unroll
    for (int jb = 0; jb < 4; ++jb)
      #pragma unroll
      for (int r = 0; r < 4; ++r) {
        float sc = S[jb][r];
        if (diag && (kv0 + jb*16 + lr4 + r) > (q0w + l15)) sc = -1e30f;
        const float p = exp2f(sc);
        sv[jb*4 + r] = p;
        sum += p;
      }
    lL += sum;

    bf16* pl = Plds[w];
    #pragma unroll
    for (int jb = 0; jb < 4; ++jb) {
      bf16 pk[4];
      #pragma unroll
      for (int r = 0; r < 4; ++r) pk[r] = __float2bfloat16(sv[jb*4 + r]);
      *(us4*)((char*)pl + l15*128 + ((((jb<<1) | (g>>1)) ^ swz) << 4) + ((g&1) << 3))
          = *(const us4*)pk;
    }

    asm volatile("s_waitcnt lgkmcnt(0)" ::: "memory");
    __builtin_amdgcn_sched_barrier(0);

    const bh8 pa0 = *(const bh8*)((const char*)pl + l15*128 + (((g    ) ^ swz) << 4));
    const bh8 pa1 = *(const bh8*)((const char*)pl + l15*128 + (((4 + g) ^ swz) << 4));
    #pragma unroll
    for (int jd = 0; jd < 8; ++jd) {
      const bh8 vf0 = *(const bh8*)&Vs[cur][(jd*16 + l15)*64 + (((g    ) ^ swz) << 3)];
      const bh8 vf1 = *(const bh8*)&Vs[cur][(jd*16 + l15)*64 + (((4 + g) ^ swz) << 3)];
      acc[jd] = __builtin_amdgcn_mfma_f32_16x16x32_bf16(pa0, vf0, acc[jd], 0,0,0);
      acc[jd] = __builtin_amdgcn_mfma_f32_16x16x32_bf16(pa1, vf1, acc[jd], 0,0,0);
    }

    asm volatile("s_waitcnt vmcnt(0)" ::: "memory");
    __syncthreads();
  }
  #undef STAGE_KV

  lL += __shfl_xor(lL, 16, 64);
  lL += __shfl_xor(lL, 32, 64);
  float lar[4];
  #pragma unroll
  for (int r = 0; r < 4; ++r)
    lar[r] = __shfl(lL, (lane & 48) | (lr4 + r), 64);
  #pragma unroll
  for (int r = 0; r < 4; ++r) {
    const float inv = 1.f / lar[r];
    const int row = q0w + lr4 + r;
    bf16* orow = att + ((size_t)(b*T_ + row))*(NH_*HD_) + h*HD_;
    #pragma unroll
    for (int jd = 0; jd < 8; ++jd)
      orow[jd*16 + l15] = __float2bfloat16(acc[jd][r] * inv);
  }
}

extern "C" void kernel_launch(void* const* d_in, const int* in_sizes, int n_in,
                              void* d_out, int out_size, void* d_ws, size_t ws_size,
                              hipStream_t stream) {
  const float* x  = (const float*)d_in[0];
  const float* Wq = (const float*)d_in[1];
  const float* Wk = (const float*)d_in[2];
  const float* Wv = (const float*)d_in[3];
  const float* Wo = (const float*)d_in[4];
  const float* qw = (const float*)d_in[5];
  const float* kw = (const float*)d_in[6];
  float* out = (float*)d_out;

  char* ws = (char*)d_ws;
  bf16* xb   = (bf16*)(ws);                  // 16MB, becomes att later
  // Wqb/Wkb/Wvb form one contiguous [3072][2048] weight concat:
  bf16* Wqb  = (bf16*)(ws + (16u<<20));      // 8MB (rows 0-2047)
  bf16* Wkb  = (bf16*)(ws + (24u<<20));      // 2MB (rows 2048-2559)
  bf16* Wvb  = (bf16*)(ws + (26u<<20));      // 2MB (rows 2560-3071)
  bf16* Wob  = (bf16*)(ws + (28u<<20));      // 8MB
  bf16* Vt   = (bf16*)(ws + (44u<<20));      // 4MB
  bf16* att  = xb;
  bf16* qkv  = (bf16*)d_out;                 // [4096][3072] bf16 = 24MB in d_out

  cvtall<<<dim3(3328), 256, 0, stream>>>(x, xb, Wq, Wqb, Wo, Wob, Wk, Wkb, Wv, Wvb);

  // fused QKV: 256 blocks (16m x 16n of 256x192), 1 block/CU, cpx = 32
  gemm_qkv192<<<dim3(256), 512, 0, stream>>>(xb, Wqb, qkv, 32);
  // merged RMSNorm/RoPE + V transpose
  postvt<<<dim3(4608), 256, 0, stream>>>(qkv, Vt, qw, kw);
  attn<<<dim3(512), 512, 0, stream>>>(qkv, Vt, att);
  // O-proj: 256 blocks (16m x 16n), XCD-chunked (cpx = 32), fp32 out
  gemm_n128<float><<<dim3(256), 512, 0, stream>>>(att, Wob, out, 2048, 16, 2048, 32);
}